// Round 7
// baseline (261.152 us; speedup 1.0000x reference)
//
#include <hip/hip_runtime.h>
#include <math.h>

// ---------------------------------------------------------------------------
// KarplusStrong: spectral-domain reformulation.
//   C_t = Wconv3( tf_t ⊙ (C_{t-1} + P_t) ),  P_t = rfft(imps_t)
//   Wconv3(V)[k] = 0.54 V[k] - 0.23 (V[k-1] + V[k+1]) (hermitian edges),
//   Im(V)=0 forced at bins 0,256. Contraction => 8-step warmup.
//
// R6: FCH 16->8 (KWARM=8). R6 counters showed ks_fwd_recur latency-bound at
// 2 waves/SIMD (grid-capped occupancy 17.7%, VALUBusy 27%): one wave = one
// serial shfl-FFT + recurrence chain. 4096 chunks = 4 waves/SIMD doubles
// latency interleaving for +33% total steps; per-SIMD serial work 0.67x.
// ---------------------------------------------------------------------------

#define N_ITER   32768
#define NBINS    257
#define BLOCK_N  512
#define KWARM    8
#define FCH      8
#define NCHUNK   (N_ITER / FCH)     // 4096
#define OUT_LEN  8388608

__device__ __forceinline__ int brev6(int x) { return (int)(__brev((unsigned)x) >> 26); }
// LDS pad for the P redistribution buffer: k + (k>>3) keeps the bit-reversed
// 64B-chunk writes ~2-way banked. PDK(256)=288 -> 289 float2 per frame.
__device__ __forceinline__ int PDK(int k) { return k + (k >> 3); }
#define PLDSZ 289

// 512-pt complex DIF FFT across one wave: reg c, lane l <-> position 64c+l.
// Natural-order input; output at position i holds X[brev9(i)].
// TS=+1: forward (e^-i); TS=-1: inverse kernel (e^+i), unnormalized.
template<int TS>
__device__ __forceinline__ void fft512_regs(float (&zr)[8], float (&zi)[8], int lane) {
  const float ts = (float)TS;
  float s1, c1;
  __sincosf((float)lane * (3.14159265358979323846f / 256.0f), &s1, &c1);
  const float v1r = c1, v1i = -ts * s1;            // e^{-i ts pi l/256}
  const float SQ = 0.70710678118654752f;
  // ---- stage m=256: pairs (c, c+4), tw = V1 * e^{-i ts pi c/4}
  {
    const float r4r[4] = {1.f, SQ, 0.f, -SQ};
    const float r4i[4] = {0.f, -ts*SQ, -ts, -ts*SQ};
    #pragma unroll
    for (int c = 0; c < 4; ++c) {
      float twr = v1r*r4r[c] - v1i*r4i[c];
      float twi = v1r*r4i[c] + v1i*r4r[c];
      float ar = zr[c], ai = zi[c], br = zr[c+4], bi = zi[c+4];
      zr[c] = ar + br; zi[c] = ai + bi;
      float dr = ar - br, di = ai - bi;
      zr[c+4] = dr*twr - di*twi; zi[c+4] = dr*twi + di*twr;
    }
  }
  const float v2r = v1r*v1r - v1i*v1i, v2i = 2.f*v1r*v1i;   // e^{-i ts pi l/128}
  // ---- stage m=128: pairs (0,2),(1,3),(4,6),(5,7); odd c gets extra (0,-ts)
  #pragma unroll
  for (int c0 = 0; c0 < 8; c0 += 4) {
    #pragma unroll
    for (int cc = 0; cc < 2; ++cc) {
      int c = c0 + cc;
      float ar = zr[c], ai = zi[c], br = zr[c+2], bi = zi[c+2];
      zr[c] = ar + br; zi[c] = ai + bi;
      float dr = ar - br, di = ai - bi;
      float qr = dr*v2r - di*v2i, qi = dr*v2i + di*v2r;
      if (cc) { float t_ = qr; qr = ts*qi; qi = -ts*t_; }   // * (0,-ts)
      zr[c+2] = qr; zi[c+2] = qi;
    }
  }
  float wr = v2r*v2r - v2i*v2i, wi = 2.f*v2r*v2i;           // e^{-i ts pi l/64}
  // ---- stage m=64: pairs (c, c+1), tw = V4
  #pragma unroll
  for (int c = 0; c < 8; c += 2) {
    float ar = zr[c], ai = zi[c], br = zr[c+1], bi = zi[c+1];
    zr[c] = ar + br; zi[c] = ai + bi;
    float dr = ar - br, di = ai - bi;
    zr[c+1] = dr*wr - di*wi; zi[c+1] = dr*wi + di*wr;
  }
  // ---- lane stages m=32..2: chain w = e^{-i ts pi l/m}; needed twiddle is
  // -w on hi lanes, so out_hi = (x_hi - x_lo)*w.
  #pragma unroll
  for (int k = 5; k >= 1; --k) {
    float nwr = wr*wr - wi*wi, nwi = 2.f*wr*wi;
    wr = nwr; wi = nwi;
    const int m = 1 << k;
    #pragma unroll
    for (int c = 0; c < 8; ++c) {
      float pr_ = __shfl_xor(zr[c], m, 64);
      float pi_ = __shfl_xor(zi[c], m, 64);
      bool hi = (lane & m) != 0;
      float sr_ = zr[c] + pr_, si_ = zi[c] + pi_;
      float dr = zr[c] - pr_, di = zi[c] - pi_;   // x_hi - x_lo on hi lanes
      float qr = dr*wr - di*wi, qi = dr*wi + di*wr;
      zr[c] = hi ? qr : sr_;
      zi[c] = hi ? qi : si_;
    }
  }
  // ---- stage m=1: tw = 1
  #pragma unroll
  for (int c = 0; c < 8; ++c) {
    float pr_ = __shfl_xor(zr[c], 1, 64);
    float pi_ = __shfl_xor(zi[c], 1, 64);
    bool hi = (lane & 1) != 0;
    zr[c] = hi ? (pr_ - zr[c]) : (zr[c] + pr_);
    zi[c] = hi ? (pi_ - zi[c]) : (zi[c] + pi_);
  }
}

// Fused K1+K2: wave = chunk j (4 chunks per 256-thread block). Per step-pair
// (t,t+1): packed FFT of both impulse frames -> hermitian split -> LDS
// redistribute -> two recurrence steps. tf double-buffered (slot reloaded at
// t+2 after consumption); noise/env prefetched across the FFT.
__global__ __launch_bounds__(256) void ks_fwd_recur(const float* __restrict__ noise,
                                                    const float* __restrict__ env,
                                                    const float* __restrict__ tfr,
                                                    const float* __restrict__ tfi,
                                                    float2* __restrict__ Cws) {
  __shared__ float2 Pld[4][2][PLDSZ];
  const int w = threadIdx.x >> 6, lane = threadIdx.x & 63;
  const int j = blockIdx.x * 4 + w;
  const int k0 = lane * 4;
  const bool l63 = (lane == 63);
  const int tprod = j * FCH;
  const int t0 = (j == 0) ? 0 : (tprod - KWARM);
  const int tend = tprod + FCH;
  float2* Pw0 = &Pld[w][0][0];
  float2* Pw1 = &Pld[w][1][0];

  float Cr[4] = {0.f,0.f,0.f,0.f}, Ci[4] = {0.f,0.f,0.f,0.f};
  float C256 = 0.f;
  float tr[2][4], ti[2][4];
  float t6r[2] = {0.f,0.f}, t6i[2] = {0.f,0.f};
  float nA[8], nB[8], eA, eB;

#define LOADTF(S, TS) do {                                                     \
    const size_t _bt = (size_t)(TS) * NBINS;                                   \
    _Pragma("unroll") for (int _i = 0; _i < 4; ++_i) {                         \
      tr[S][_i] = tfr[_bt + k0 + _i];                                          \
      ti[S][_i] = tfi[_bt + k0 + _i];                                          \
    }                                                                          \
    if (l63) { t6r[S] = tfr[_bt + 256]; t6i[S] = tfi[_bt + 256]; }             \
  } while (0)

#define LOADNOISE(TA, TB) do {                                                 \
    const float* _pa = noise + (size_t)(TA) * BLOCK_N;                         \
    const float* _pb = noise + (size_t)(TB) * BLOCK_N;                         \
    _Pragma("unroll") for (int _c = 0; _c < 8; ++_c) {                         \
      nA[_c] = _pa[64*_c + lane];                                              \
      nB[_c] = _pb[64*_c + lane];                                              \
    }                                                                          \
    eA = env[TA]; eB = env[TB];                                                \
  } while (0)

// One recurrence step: consume tf slot S and P values (PR/PI/P6R/P6I), then
// reload slot S with row T+2.
#define STEP(S, T, PR, PI, P6R, P6I) do {                                      \
    const int _t = (T);                                                        \
    float Vr[4], Vi[4];                                                        \
    _Pragma("unroll") for (int _i = 0; _i < 4; ++_i) {                         \
      float Ur = Cr[_i] + PR[_i], Ui = Ci[_i] + PI[_i];                        \
      Vr[_i] = tr[S][_i]*Ur - ti[S][_i]*Ui;                                    \
      Vi[_i] = tr[S][_i]*Ui + ti[S][_i]*Ur;                                    \
    }                                                                          \
    if (lane == 0) Vi[0] = 0.f;                                                \
    float U6r = C256 + P6R, U6i = P6I;                                         \
    float V6r = t6r[S]*U6r - t6i[S]*U6i;                                       \
    int _tf = _t + 2; if (_tf > N_ITER - 1) _tf = N_ITER - 1;                  \
    LOADTF(S, _tf);                                                            \
    float Lr = __shfl_up(Vr[3], 1),   Li = __shfl_up(Vi[3], 1);                \
    float Rr = __shfl_down(Vr[0], 1), Ri = __shfl_down(Vi[0], 1);              \
    if (lane == 0) { Lr = Vr[1]; Li = -Vi[1]; }                                \
    if (l63)       { Rr = V6r;   Ri = 0.f; }                                   \
    Cr[0] = 0.54f*Vr[0] - 0.23f*(Lr    + Vr[1]);                               \
    Ci[0] = 0.54f*Vi[0] - 0.23f*(Li    + Vi[1]);                               \
    Cr[1] = 0.54f*Vr[1] - 0.23f*(Vr[0] + Vr[2]);                               \
    Ci[1] = 0.54f*Vi[1] - 0.23f*(Vi[0] + Vi[2]);                               \
    Cr[2] = 0.54f*Vr[2] - 0.23f*(Vr[1] + Vr[3]);                               \
    Ci[2] = 0.54f*Vi[2] - 0.23f*(Vi[1] + Vi[3]);                               \
    Cr[3] = 0.54f*Vr[3] - 0.23f*(Vr[2] + Rr);                                  \
    Ci[3] = 0.54f*Vi[3] - 0.23f*(Vi[2] + Ri);                                  \
    C256  = 0.54f*V6r   - 0.46f*Vr[3];                                         \
    if (_t >= tprod) {                                                         \
      const size_t _bo = (size_t)_t * NBINS + k0;                              \
      Cws[_bo + 0] = make_float2(Cr[0], Ci[0]);                                \
      Cws[_bo + 1] = make_float2(Cr[1], Ci[1]);                                \
      Cws[_bo + 2] = make_float2(Cr[2], Ci[2]);                                \
      Cws[_bo + 3] = make_float2(Cr[3], Ci[3]);                                \
      if (l63) Cws[(size_t)_t * NBINS + 256] = make_float2(C256, 0.f);         \
    }                                                                          \
  } while (0)

  LOADTF(0, t0);
  LOADTF(1, t0 + 1);
  LOADNOISE(t0, t0 + 1);

  for (int t = t0; t < tend; t += 2) {     // span 8 or 16: always even
    // Build impulse pair from prefetched noise/env; free the regs; prefetch.
    const float ea2 = eA * eA, eb2 = eB * eB;
    float zr[8], zi[8];
    #pragma unroll
    for (int c = 0; c < 8; ++c) {
      zr[c] = (2.f * nA[c] - 1.f) * ea2;
      zi[c] = (2.f * nB[c] - 1.f) * eb2;
    }
    {
      int ta = t + 2; if (ta > N_ITER - 1) ta = N_ITER - 1;
      int tb = t + 3; if (tb > N_ITER - 1) tb = N_ITER - 1;
      LOADNOISE(ta, tb);
    }
    // Packed forward FFT + hermitian split.
    fft512_regs<1>(zr, zi, lane);
    float mr[8], mi[8];
    {
      int r_ = brev6(lane);
      int lam = brev6((64 - r_) & 63);
      mr[0] = __shfl(zr[0], lam, 64); mi[0] = __shfl(zi[0], lam, 64);
    }
    mr[1] = __shfl_xor(zr[1], 63, 64); mi[1] = __shfl_xor(zi[1], 63, 64);
    mr[2] = __shfl_xor(zr[3], 63, 64); mi[2] = __shfl_xor(zi[3], 63, 64);
    mr[3] = __shfl_xor(zr[2], 63, 64); mi[3] = __shfl_xor(zi[2], 63, 64);
    mr[4] = __shfl_xor(zr[7], 63, 64); mi[4] = __shfl_xor(zi[7], 63, 64);
    mr[5] = __shfl_xor(zr[6], 63, 64); mi[5] = __shfl_xor(zi[6], 63, 64);
    mr[6] = __shfl_xor(zr[5], 63, 64); mi[6] = __shfl_xor(zi[5], 63, 64);
    mr[7] = __shfl_xor(zr[4], 63, 64); mi[7] = __shfl_xor(zi[4], 63, 64);
    const int r = brev6(lane);
    const int CB3[8] = {0,4,2,6,1,5,3,7};
    if ((lane & 1) == 0) {           // even lanes: k = 8r+s < 256
      #pragma unroll
      for (int s = 0; s < 8; ++s) {
        int c = CB3[s];
        int k = 8*r + s;
        Pw0[PDK(k)] = make_float2(0.5f*(zr[c] + mr[c]), 0.5f*(zi[c] - mi[c]));
        Pw1[PDK(k)] = make_float2(0.5f*(zi[c] + mi[c]), 0.5f*(mr[c] - zr[c]));
      }
    } else if (lane == 1) {          // r=32, reg0 -> k=256 (self-mirror)
      Pw0[PDK(256)] = make_float2(0.5f*(zr[0] + mr[0]), 0.5f*(zi[0] - mi[0]));
      Pw1[PDK(256)] = make_float2(0.5f*(zi[0] + mi[0]), 0.5f*(mr[0] - zr[0]));
    }
    // Redistribute to recurrence layout (same-wave LDS: program-ordered, no
    // barrier needed; compiler inserts the lgkmcnt wait).
    float pr0[4], pi0[4], pr1[4], pi1[4];
    float p60r = 0.f, p60i = 0.f, p61r = 0.f, p61i = 0.f;
    #pragma unroll
    for (int i = 0; i < 4; ++i) {
      float2 q0 = Pw0[PDK(k0 + i)];
      float2 q1 = Pw1[PDK(k0 + i)];
      pr0[i] = q0.x; pi0[i] = q0.y;
      pr1[i] = q1.x; pi1[i] = q1.y;
    }
    if (l63) {
      float2 q0 = Pw0[PDK(256)]; p60r = q0.x; p60i = q0.y;
      float2 q1 = Pw1[PDK(256)]; p61r = q1.x; p61i = q1.y;
    }
    STEP(0, t,     pr0, pi0, p60r, p60i);
    STEP(1, t + 1, pr1, pi1, p61r, p61i);
  }
#undef LOADTF
#undef LOADNOISE
#undef STEP
}

// K3a: wave u packs frames (2u,2u+1): z = SA + i SB built directly from Cws
// (conjugated mirror reads for k>256). After inverse FFT, lane l holds
// samples [8*brev6(l), +8) of both frames. Even lanes store blk fa-lower and
// emit odd out row fbr (fb lower + fa upper via shfl_xor(.,1)); odd lanes
// store blk fbr-upper.
__global__ __launch_bounds__(256) void ks_inv_fft(const float2* __restrict__ Cws,
                                                  const float* __restrict__ noise,
                                                  const float* __restrict__ env,
                                                  float* __restrict__ blk,
                                                  float* __restrict__ out) {
  const int tid = threadIdx.x;
  const int w = tid >> 6, lane = tid & 63;
  const int u = blockIdx.x * 4 + w;
  const int fa = 2 * u, fbr = 2 * u + 1;
  const int rowA = (u == 0) ? 0 : (2 * u - 1);
  const int rowB = 2 * u;
  const float zA = (u == 0) ? 0.f : 1.f;
  const float2* CA = Cws + (size_t)rowA * NBINS;
  const float2* CB = Cws + (size_t)rowB * NBINS;
  const float sc = 1.0f / 512.0f;
  float zr[8], zi[8];
  #pragma unroll
  for (int c = 0; c < 8; ++c) {
    int k = 64 * c + lane;
    bool mir = (k > 256);
    int idx = mir ? (512 - k) : k;
    float2 a = CA[idx]; a.x *= zA; a.y *= zA;
    float2 b = CB[idx];
    float ay = mir ? -a.y : a.y;
    float by = mir ?  b.y : -b.y;
    zr[c] = sc * (a.x + by);     // Re(SA + iSB) with conj on mirror
    zi[c] = sc * (b.x + ay);
  }
  fft512_regs<-1>(zr, zi, lane);
  const int r = brev6(lane);
  const int base = 8 * r;
  const float ea = env[fa];  const float ea2 = ea * ea;
  const float eb = env[fbr]; const float eb2 = eb * eb;
  const float* na = noise + (size_t)fa  * BLOCK_N + base;
  const float* nb = noise + (size_t)fbr * BLOCK_N + base;
  float Aa[8], Bb[8];
  *(float4*)(&Aa[0]) = *(const float4*)(na);
  *(float4*)(&Aa[4]) = *(const float4*)(na + 4);
  *(float4*)(&Bb[0]) = *(const float4*)(nb);
  *(float4*)(&Bb[4]) = *(const float4*)(nb + 4);
  const int CB3[8] = {0,4,2,6,1,5,3,7};
  float va[8], vb[8];
  #pragma unroll
  for (int s = 0; s < 8; ++s) {
    int c = CB3[s];
    va[s] = zr[c] + (2.f * Aa[s] - 1.f) * ea2;
    vb[s] = zi[c] + (2.f * Bb[s] - 1.f) * eb2;
  }
  float sva[8];
  #pragma unroll
  for (int s = 0; s < 8; ++s) sva[s] = __shfl_xor(va[s], 1, 64);
  if ((lane & 1) == 0) {           // r < 32: lower halves
    float* d = blk + (size_t)fa * BLOCK_N + base;
    ((float4*)d)[0] = make_float4(va[0], va[1], va[2], va[3]);
    ((float4*)d)[1] = make_float4(va[4], va[5], va[6], va[7]);
    float* o = out + (size_t)fbr * 256 + base;
    ((float4*)o)[0] = make_float4(vb[0]+sva[0], vb[1]+sva[1], vb[2]+sva[2], vb[3]+sva[3]);
    ((float4*)o)[1] = make_float4(vb[4]+sva[4], vb[5]+sva[5], vb[6]+sva[6], vb[7]+sva[7]);
  } else {                          // r >= 32: upper halves (base in [256,512))
    float* d = blk + (size_t)fbr * BLOCK_N + base;
    ((float4*)d)[0] = make_float4(vb[0], vb[1], vb[2], vb[3]);
    ((float4*)d)[1] = make_float4(vb[4], vb[5], vb[6], vb[7]);
  }
}

// K3b: even out rows only: out[f][n] = blk[f][n] + blk[f-1][n+256].
__global__ __launch_bounds__(256) void ks_ola(const float* __restrict__ blk,
                                              float* __restrict__ out) {
  const int g = blockIdx.x * 256 + threadIdx.x;
  const int row_e = g >> 6;            // 0..16383
  const int f = row_e << 1;
  const int n = (g & 63) << 2;
  float4 v = *(const float4*)(blk + (size_t)f * BLOCK_N + n);
  if (row_e > 0) {
    float4 uu = *(const float4*)(blk + (size_t)(f - 1) * BLOCK_N + 256 + n);
    v.x += uu.x; v.y += uu.y; v.z += uu.z; v.w += uu.w;
  }
  *(float4*)(out + (size_t)f * 256 + n) = v;
}

extern "C" void kernel_launch(void* const* d_in, const int* in_sizes, int n_in,
                              void* d_out, int out_size, void* d_ws, size_t ws_size,
                              hipStream_t stream) {
  (void)in_sizes; (void)n_in; (void)ws_size; (void)out_size;
  const float* noise = (const float*)d_in[1];
  const float* env   = (const float*)d_in[2];
  const float* tfr   = (const float*)d_in[3];
  const float* tfi   = (const float*)d_in[4];
  float* out = (float*)d_out;

  float2* Cws = (float2*)((char*)d_ws + (size_t)N_ITER * NBINS * sizeof(float2));
  float*  blk = (float*)d_ws;   // 67.1 MB region, disjoint from Cws
  // ws requirement: 2 * 32768 * 257 * 8 = 134,742,016 bytes.

  ks_fwd_recur<<<dim3(NCHUNK / 4), dim3(256), 0, stream>>>(noise, env, tfr, tfi, Cws);
  ks_inv_fft<<<dim3(N_ITER / 8), dim3(256), 0, stream>>>(Cws, noise, env, blk, out);
  ks_ola<<<dim3(OUT_LEN / 2 / 1024), dim3(256), 0, stream>>>(blk, out);
}

// Round 8
// 222.944 us; speedup vs baseline: 1.1714x; 1.1714x over previous
//
#include <hip/hip_runtime.h>
#include <math.h>

// ---------------------------------------------------------------------------
// KarplusStrong, fully fused single kernel.
//   C_t = Wconv3( tf_t ⊙ (C_{t-1} + P_t) ),  P_t = rfft(imps_t)  (spectral
//   recurrence, 3-tap hamming conv, Im=0 at bins 0,256). Contraction
//   |A_t| <= 0.283 => 6-step zero-state warmup per 8-frame chunk; the last
//   two warmup C's (error ~0.27^4) also feed the chunk's first output rows.
//
// R7: ks_fwd_recur + ks_inv_fft + ks_ola fused into ks_mega. Each chunk-wave:
//   per step-pair: packed fwd FFT of impulses -> hermitian split -> LDS
//   redistribute -> 2 recurrence steps (C stashed to LDS in recur layout) ->
//   packed INVERSE FFT of (C[t],C[t+1]) read back from LDS in spectrum layout
//   (mirror-conj) -> + impulses -> OLA rows via shfl_xor half-merge with
//   running pvb. Eliminates Cws (66W+84R MB), blk (34W+50R MB), 2 launches.
//   All building blocks verbatim from the R5/R6 correctness-verified kernels;
//   new glue is only the C->LDS->spectrum conversion and the emission guards.
// Emission map (wave j, rows 8j..8j+7): pair at t emits row t+1 (va + pvb^)
//   when t>=8j, and row t+2 (vb + va^) when t+2<=8j+7; inv pairs run for
//   t>=8j-2. j=0: row 0 = imps0 lower half (exact pre-pair, pvb seed).
// ---------------------------------------------------------------------------

#define N_ITER   32768
#define NBINS    257
#define BLOCK_N  512
#define FCH      8
#define NCHUNK   (N_ITER / FCH)     // 4096 waves
#define OUT_LEN  8388608

__device__ __forceinline__ int brev6(int x) { return (int)(__brev((unsigned)x) >> 26); }
__device__ __forceinline__ int PDK(int k) { return k + (k >> 3); }
#define PLDSZ 289

// 512-pt complex DIF FFT across one wave: reg c, lane l <-> position 64c+l.
// Natural-order input; output at position i holds X[brev9(i)].
// TS=+1: forward (e^-i); TS=-1: inverse kernel (e^+i), unnormalized.
template<int TS>
__device__ __forceinline__ void fft512_regs(float (&zr)[8], float (&zi)[8], int lane) {
  const float ts = (float)TS;
  float s1, c1;
  __sincosf((float)lane * (3.14159265358979323846f / 256.0f), &s1, &c1);
  const float v1r = c1, v1i = -ts * s1;            // e^{-i ts pi l/256}
  const float SQ = 0.70710678118654752f;
  {
    const float r4r[4] = {1.f, SQ, 0.f, -SQ};
    const float r4i[4] = {0.f, -ts*SQ, -ts, -ts*SQ};
    #pragma unroll
    for (int c = 0; c < 4; ++c) {
      float twr = v1r*r4r[c] - v1i*r4i[c];
      float twi = v1r*r4i[c] + v1i*r4r[c];
      float ar = zr[c], ai = zi[c], br = zr[c+4], bi = zi[c+4];
      zr[c] = ar + br; zi[c] = ai + bi;
      float dr = ar - br, di = ai - bi;
      zr[c+4] = dr*twr - di*twi; zi[c+4] = dr*twi + di*twr;
    }
  }
  const float v2r = v1r*v1r - v1i*v1i, v2i = 2.f*v1r*v1i;
  #pragma unroll
  for (int c0 = 0; c0 < 8; c0 += 4) {
    #pragma unroll
    for (int cc = 0; cc < 2; ++cc) {
      int c = c0 + cc;
      float ar = zr[c], ai = zi[c], br = zr[c+2], bi = zi[c+2];
      zr[c] = ar + br; zi[c] = ai + bi;
      float dr = ar - br, di = ai - bi;
      float qr = dr*v2r - di*v2i, qi = dr*v2i + di*v2r;
      if (cc) { float t_ = qr; qr = ts*qi; qi = -ts*t_; }
      zr[c+2] = qr; zi[c+2] = qi;
    }
  }
  float wr = v2r*v2r - v2i*v2i, wi = 2.f*v2r*v2i;
  #pragma unroll
  for (int c = 0; c < 8; c += 2) {
    float ar = zr[c], ai = zi[c], br = zr[c+1], bi = zi[c+1];
    zr[c] = ar + br; zi[c] = ai + bi;
    float dr = ar - br, di = ai - bi;
    zr[c+1] = dr*wr - di*wi; zi[c+1] = dr*wi + di*wr;
  }
  // lane stages m=32..2: chain w; needed twiddle is -w on hi lanes,
  // so out_hi = (x_hi - x_lo)*w.
  #pragma unroll
  for (int k = 5; k >= 1; --k) {
    float nwr = wr*wr - wi*wi, nwi = 2.f*wr*wi;
    wr = nwr; wi = nwi;
    const int m = 1 << k;
    #pragma unroll
    for (int c = 0; c < 8; ++c) {
      float pr_ = __shfl_xor(zr[c], m, 64);
      float pi_ = __shfl_xor(zi[c], m, 64);
      bool hi = (lane & m) != 0;
      float sr_ = zr[c] + pr_, si_ = zi[c] + pi_;
      float dr = zr[c] - pr_, di = zi[c] - pi_;
      float qr = dr*wr - di*wi, qi = dr*wi + di*wr;
      zr[c] = hi ? qr : sr_;
      zi[c] = hi ? qi : si_;
    }
  }
  #pragma unroll
  for (int c = 0; c < 8; ++c) {
    float pr_ = __shfl_xor(zr[c], 1, 64);
    float pi_ = __shfl_xor(zi[c], 1, 64);
    bool hi = (lane & 1) != 0;
    zr[c] = hi ? (pr_ - zr[c]) : (zr[c] + pr_);
    zi[c] = hi ? (pi_ - zi[c]) : (zi[c] + pi_);
  }
}

__global__ __launch_bounds__(256) void ks_mega(const float* __restrict__ noise,
                                               const float* __restrict__ env,
                                               const float* __restrict__ tfr,
                                               const float* __restrict__ tfi,
                                               float* __restrict__ out) {
  __shared__ float2 Pld[4][2][PLDSZ];
  __shared__ float2 LcS[4][2][PLDSZ];
  const int w = threadIdx.x >> 6, lane = threadIdx.x & 63;
  const int j = blockIdx.x * 4 + w;
  const int k0 = lane * 4;
  const bool l63 = (lane == 63);
  const int rr = brev6(lane);
  const int base = 8 * rr;
  const int tprod = j * FCH;
  const int t0 = (j == 0) ? 0 : (tprod - 6);
  const int tend = tprod + FCH;
  float2* Pw0 = &Pld[w][0][0];
  float2* Pw1 = &Pld[w][1][0];
  float2* Lc0 = &LcS[w][0][0];
  float2* Lc1 = &LcS[w][1][0];
  const float sc = 1.0f / 512.0f;
  const int CB3[8] = {0,4,2,6,1,5,3,7};

  float Cr[4] = {0.f,0.f,0.f,0.f}, Ci[4] = {0.f,0.f,0.f,0.f};
  float C256 = 0.f;
  float tr[2][4], ti[2][4];
  float t6r[2] = {0.f,0.f}, t6i[2] = {0.f,0.f};
  float nA[8], nB[8], eA, eB;
  float pvb[8] = {0.f,0.f,0.f,0.f,0.f,0.f,0.f,0.f};

  // j==0 pre-pair: frame -1 = 0, frame 0 = imps0 (zero spectrum). Emit row 0
  // (= imps0 lower half) and seed pvb with frame 0.
  if (j == 0) {
    const float e0 = env[0]; const float e02 = e0 * e0;
    const float* n0 = noise + base;
    float q[8];
    *(float4*)(&q[0]) = *(const float4*)(n0);
    *(float4*)(&q[4]) = *(const float4*)(n0 + 4);
    #pragma unroll
    for (int s = 0; s < 8; ++s) pvb[s] = (2.f * q[s] - 1.f) * e02;
    if (!(lane & 1)) {
      float* o = out + base;
      ((float4*)o)[0] = make_float4(pvb[0], pvb[1], pvb[2], pvb[3]);
      ((float4*)o)[1] = make_float4(pvb[4], pvb[5], pvb[6], pvb[7]);
    }
  }

#define LOADTF(S, TS_) do {                                                    \
    const size_t _bt = (size_t)(TS_) * NBINS;                                  \
    _Pragma("unroll") for (int _i = 0; _i < 4; ++_i) {                         \
      tr[S][_i] = tfr[_bt + k0 + _i];                                          \
      ti[S][_i] = tfi[_bt + k0 + _i];                                          \
    }                                                                          \
    if (l63) { t6r[S] = tfr[_bt + 256]; t6i[S] = tfi[_bt + 256]; }             \
  } while (0)

#define LOADNOISE(TA, TB) do {                                                 \
    const float* _pa = noise + (size_t)(TA) * BLOCK_N;                         \
    const float* _pb = noise + (size_t)(TB) * BLOCK_N;                         \
    _Pragma("unroll") for (int _c = 0; _c < 8; ++_c) {                         \
      nA[_c] = _pa[64*_c + lane];                                              \
      nB[_c] = _pb[64*_c + lane];                                              \
    }                                                                          \
    eA = env[TA]; eB = env[TB];                                                \
  } while (0)

// One recurrence step; stash C_t to LDS (recur layout) when it will feed an
// inverse FFT (t >= tprod-2). Math verbatim from verified R5/R6 STEP.
#define STEP(S, T, PR, PI, P6R, P6I) do {                                      \
    const int _t = (T);                                                        \
    float Vr[4], Vi[4];                                                        \
    _Pragma("unroll") for (int _i = 0; _i < 4; ++_i) {                         \
      float Ur = Cr[_i] + PR[_i], Ui = Ci[_i] + PI[_i];                        \
      Vr[_i] = tr[S][_i]*Ur - ti[S][_i]*Ui;                                    \
      Vi[_i] = tr[S][_i]*Ui + ti[S][_i]*Ur;                                    \
    }                                                                          \
    if (lane == 0) Vi[0] = 0.f;                                                \
    float U6r = C256 + P6R, U6i = P6I;                                         \
    float V6r = t6r[S]*U6r - t6i[S]*U6i;                                       \
    int _tf = _t + 2; if (_tf > N_ITER - 1) _tf = N_ITER - 1;                  \
    LOADTF(S, _tf);                                                            \
    float Lr = __shfl_up(Vr[3], 1),   Li = __shfl_up(Vi[3], 1);                \
    float Rr = __shfl_down(Vr[0], 1), Ri = __shfl_down(Vi[0], 1);              \
    if (lane == 0) { Lr = Vr[1]; Li = -Vi[1]; }                                \
    if (l63)       { Rr = V6r;   Ri = 0.f; }                                   \
    Cr[0] = 0.54f*Vr[0] - 0.23f*(Lr    + Vr[1]);                               \
    Ci[0] = 0.54f*Vi[0] - 0.23f*(Li    + Vi[1]);                               \
    Cr[1] = 0.54f*Vr[1] - 0.23f*(Vr[0] + Vr[2]);                               \
    Ci[1] = 0.54f*Vi[1] - 0.23f*(Vi[0] + Vi[2]);                               \
    Cr[2] = 0.54f*Vr[2] - 0.23f*(Vr[1] + Vr[3]);                               \
    Ci[2] = 0.54f*Vi[2] - 0.23f*(Vi[1] + Vi[3]);                               \
    Cr[3] = 0.54f*Vr[3] - 0.23f*(Vr[2] + Rr);                                  \
    Ci[3] = 0.54f*Vi[3] - 0.23f*(Vi[2] + Ri);                                  \
    C256  = 0.54f*V6r   - 0.46f*Vr[3];                                         \
    if (_t >= tprod - 2) {                                                     \
      float2* _Ls = ((_t) & 1) ? Lc1 : Lc0;                                    \
      _Ls[PDK(k0 + 0)] = make_float2(Cr[0], Ci[0]);                            \
      _Ls[PDK(k0 + 1)] = make_float2(Cr[1], Ci[1]);                            \
      _Ls[PDK(k0 + 2)] = make_float2(Cr[2], Ci[2]);                            \
      _Ls[PDK(k0 + 3)] = make_float2(Cr[3], Ci[3]);                            \
      if (l63) _Ls[PDK(256)] = make_float2(C256, 0.f);                         \
    }                                                                          \
  } while (0)

  LOADTF(0, t0);
  LOADTF(1, t0 + 1);
  LOADNOISE(t0, t0 + 1);

  for (int t = t0; t < tend; t += 2) {
    // ---- packed forward FFT of impulses (t, t+1) ----
    const float ea2 = eA * eA, eb2 = eB * eB;
    float zr[8], zi[8];
    #pragma unroll
    for (int c = 0; c < 8; ++c) {
      zr[c] = (2.f * nA[c] - 1.f) * ea2;
      zi[c] = (2.f * nB[c] - 1.f) * eb2;
    }
    {
      int ta = t + 2; if (ta > N_ITER - 1) ta = N_ITER - 1;
      int tb = t + 3; if (tb > N_ITER - 1) tb = N_ITER - 1;
      LOADNOISE(ta, tb);
    }
    fft512_regs<1>(zr, zi, lane);
    float mr[8], mi[8];
    {
      int r_ = brev6(lane);
      int lam = brev6((64 - r_) & 63);
      mr[0] = __shfl(zr[0], lam, 64); mi[0] = __shfl(zi[0], lam, 64);
    }
    mr[1] = __shfl_xor(zr[1], 63, 64); mi[1] = __shfl_xor(zi[1], 63, 64);
    mr[2] = __shfl_xor(zr[3], 63, 64); mi[2] = __shfl_xor(zi[3], 63, 64);
    mr[3] = __shfl_xor(zr[2], 63, 64); mi[3] = __shfl_xor(zi[2], 63, 64);
    mr[4] = __shfl_xor(zr[7], 63, 64); mi[4] = __shfl_xor(zi[7], 63, 64);
    mr[5] = __shfl_xor(zr[6], 63, 64); mi[5] = __shfl_xor(zi[6], 63, 64);
    mr[6] = __shfl_xor(zr[5], 63, 64); mi[6] = __shfl_xor(zi[5], 63, 64);
    mr[7] = __shfl_xor(zr[4], 63, 64); mi[7] = __shfl_xor(zi[4], 63, 64);
    if (!(lane & 1)) {
      #pragma unroll
      for (int s = 0; s < 8; ++s) {
        int c = CB3[s];
        int k = 8 * rr + s;
        Pw0[PDK(k)] = make_float2(0.5f*(zr[c] + mr[c]), 0.5f*(zi[c] - mi[c]));
        Pw1[PDK(k)] = make_float2(0.5f*(zi[c] + mi[c]), 0.5f*(mr[c] - zr[c]));
      }
    } else if (lane == 1) {
      Pw0[PDK(256)] = make_float2(0.5f*(zr[0] + mr[0]), 0.5f*(zi[0] - mi[0]));
      Pw1[PDK(256)] = make_float2(0.5f*(zi[0] + mi[0]), 0.5f*(mr[0] - zr[0]));
    }
    float pr0[4], pi0[4], pr1[4], pi1[4];
    float p60r = 0.f, p60i = 0.f, p61r = 0.f, p61i = 0.f;
    #pragma unroll
    for (int i = 0; i < 4; ++i) {
      float2 q0 = Pw0[PDK(k0 + i)];
      float2 q1 = Pw1[PDK(k0 + i)];
      pr0[i] = q0.x; pi0[i] = q0.y;
      pr1[i] = q1.x; pi1[i] = q1.y;
    }
    if (l63) {
      float2 q0 = Pw0[PDK(256)]; p60r = q0.x; p60i = q0.y;
      float2 q1 = Pw1[PDK(256)]; p61r = q1.x; p61i = q1.y;
    }
    // ---- two recurrence steps (stash C to LDS when inv-active) ----
    STEP(0, t,     pr0, pi0, p60r, p60i);
    STEP(1, t + 1, pr1, pi1, p61r, p61i);
    // ---- packed inverse FFT of (C[t], C[t+1]) -> frames (t+1, t+2) ----
    if (t >= tprod - 2) {
      float izr[8], izi[8];
      #pragma unroll
      for (int c = 0; c < 8; ++c) {
        int k = 64 * c + lane;
        bool mir = (k > 256);
        int idx = mir ? (512 - k) : k;
        float2 a = Lc0[PDK(idx)];
        float2 b = Lc1[PDK(idx)];
        float ay = mir ? -a.y : a.y;
        float by = mir ?  b.y : -b.y;
        izr[c] = sc * (a.x + by);
        izi[c] = sc * (b.x + ay);
      }
      fft512_regs<-1>(izr, izi, lane);
      const int fa = t + 1;
      int fb = t + 2; int nfb = (fb > N_ITER - 1) ? (N_ITER - 1) : fb;
      const float efa = env[fa];  const float efa2 = efa * efa;
      const float efb = env[nfb]; const float efb2 = efb * efb;
      const float* na_ = noise + (size_t)fa  * BLOCK_N + base;
      const float* nb_ = noise + (size_t)nfb * BLOCK_N + base;
      float Aa[8], Bb[8];
      *(float4*)(&Aa[0]) = *(const float4*)(na_);
      *(float4*)(&Aa[4]) = *(const float4*)(na_ + 4);
      *(float4*)(&Bb[0]) = *(const float4*)(nb_);
      *(float4*)(&Bb[4]) = *(const float4*)(nb_ + 4);
      float va[8], vb[8];
      #pragma unroll
      for (int s = 0; s < 8; ++s) {
        int c = CB3[s];
        va[s] = izr[c] + (2.f * Aa[s] - 1.f) * efa2;
        vb[s] = izi[c] + (2.f * Bb[s] - 1.f) * efb2;
      }
      float sva[8], spv[8];
      #pragma unroll
      for (int s = 0; s < 8; ++s) {
        sva[s] = __shfl_xor(va[s], 1, 64);
        spv[s] = __shfl_xor(pvb[s], 1, 64);
      }
      if (!(lane & 1)) {
        if (t >= tprod) {                       // row fa = va lower + pvb upper
          float* o = out + (size_t)fa * 256 + base;
          ((float4*)o)[0] = make_float4(va[0]+spv[0], va[1]+spv[1], va[2]+spv[2], va[3]+spv[3]);
          ((float4*)o)[1] = make_float4(va[4]+spv[4], va[5]+spv[5], va[6]+spv[6], va[7]+spv[7]);
        }
        if (fb <= tprod + 7) {                  // row fb = vb lower + va upper
          float* o = out + (size_t)fb * 256 + base;
          ((float4*)o)[0] = make_float4(vb[0]+sva[0], vb[1]+sva[1], vb[2]+sva[2], vb[3]+sva[3]);
          ((float4*)o)[1] = make_float4(vb[4]+sva[4], vb[5]+sva[5], vb[6]+sva[6], vb[7]+sva[7]);
        }
      }
      #pragma unroll
      for (int s = 0; s < 8; ++s) pvb[s] = vb[s];
    }
  }
#undef LOADTF
#undef LOADNOISE
#undef STEP
}

extern "C" void kernel_launch(void* const* d_in, const int* in_sizes, int n_in,
                              void* d_out, int out_size, void* d_ws, size_t ws_size,
                              hipStream_t stream) {
  (void)in_sizes; (void)n_in; (void)ws_size; (void)out_size; (void)d_ws;
  const float* noise = (const float*)d_in[1];
  const float* env   = (const float*)d_in[2];
  const float* tfr   = (const float*)d_in[3];
  const float* tfi   = (const float*)d_in[4];
  float* out = (float*)d_out;
  // Single fused kernel; no workspace needed (every out row fully written).
  ks_mega<<<dim3(NCHUNK / 4), dim3(256), 0, stream>>>(noise, env, tfr, tfi, out);
}

// Round 9
// 215.573 us; speedup vs baseline: 1.2114x; 1.0342x over previous
//
#include <hip/hip_runtime.h>
#include <math.h>

// ---------------------------------------------------------------------------
// KarplusStrong, fully fused single kernel (R8-verified structure).
//   C_t = Wconv3( tf_t ⊙ (C_{t-1} + P_t) ),  P_t = rfft(imps_t)  (spectral
//   recurrence, 3-tap hamming conv, Im=0 at bins 0,256). Contraction =>
//   6-step warmup per 8-frame chunk.
//
// R8: shuffle-pipe offload. __shfl_* = ds_bpermute = LDS-pipe ops; the DS
// pipe (per-CU) was the bottleneck (~280 DS ops/pair). The xor-1 and xor-2
// exchanges move to DPP quad_perm (VALU, no DS traffic): FFT stages m=2,m=1
// in both FFTs + the OLA epilogue half-merges. ~28% of DS load removed.
// Everything else verbatim from R8 (passed, absmax 7.8e-3).
// ---------------------------------------------------------------------------

#define N_ITER   32768
#define NBINS    257
#define BLOCK_N  512
#define FCH      8
#define NCHUNK   (N_ITER / FCH)     // 4096 waves
#define OUT_LEN  8388608

__device__ __forceinline__ int brev6(int x) { return (int)(__brev((unsigned)x) >> 26); }
__device__ __forceinline__ int PDK(int k) { return k + (k >> 3); }
#define PLDSZ 289

// DPP quad_perm exchange (VALU, not LDS pipe). CTRL=0xB1: lane^1; 0x4E: lane^2.
// Only used in fully-active code (FFT body, pre-branch epilogue).
template<int CTRL>
__device__ __forceinline__ float dppq(float x) {
  union { float f; int i; } u; u.f = x;
  u.i = __builtin_amdgcn_update_dpp(u.i, u.i, CTRL, 0xF, 0xF, false);
  return u.f;
}
#define DPP_XOR1 0xB1
#define DPP_XOR2 0x4E

// 512-pt complex DIF FFT across one wave: reg c, lane l <-> position 64c+l.
// Natural-order input; output at position i holds X[brev9(i)].
// TS=+1: forward (e^-i); TS=-1: inverse kernel (e^+i), unnormalized.
template<int TS>
__device__ __forceinline__ void fft512_regs(float (&zr)[8], float (&zi)[8], int lane) {
  const float ts = (float)TS;
  float s1, c1;
  __sincosf((float)lane * (3.14159265358979323846f / 256.0f), &s1, &c1);
  const float v1r = c1, v1i = -ts * s1;            // e^{-i ts pi l/256}
  const float SQ = 0.70710678118654752f;
  {
    const float r4r[4] = {1.f, SQ, 0.f, -SQ};
    const float r4i[4] = {0.f, -ts*SQ, -ts, -ts*SQ};
    #pragma unroll
    for (int c = 0; c < 4; ++c) {
      float twr = v1r*r4r[c] - v1i*r4i[c];
      float twi = v1r*r4i[c] + v1i*r4r[c];
      float ar = zr[c], ai = zi[c], br = zr[c+4], bi = zi[c+4];
      zr[c] = ar + br; zi[c] = ai + bi;
      float dr = ar - br, di = ai - bi;
      zr[c+4] = dr*twr - di*twi; zi[c+4] = dr*twi + di*twr;
    }
  }
  const float v2r = v1r*v1r - v1i*v1i, v2i = 2.f*v1r*v1i;
  #pragma unroll
  for (int c0 = 0; c0 < 8; c0 += 4) {
    #pragma unroll
    for (int cc = 0; cc < 2; ++cc) {
      int c = c0 + cc;
      float ar = zr[c], ai = zi[c], br = zr[c+2], bi = zi[c+2];
      zr[c] = ar + br; zi[c] = ai + bi;
      float dr = ar - br, di = ai - bi;
      float qr = dr*v2r - di*v2i, qi = dr*v2i + di*v2r;
      if (cc) { float t_ = qr; qr = ts*qi; qi = -ts*t_; }
      zr[c+2] = qr; zi[c+2] = qi;
    }
  }
  float wr = v2r*v2r - v2i*v2i, wi = 2.f*v2r*v2i;
  #pragma unroll
  for (int c = 0; c < 8; c += 2) {
    float ar = zr[c], ai = zi[c], br = zr[c+1], bi = zi[c+1];
    zr[c] = ar + br; zi[c] = ai + bi;
    float dr = ar - br, di = ai - bi;
    zr[c+1] = dr*wr - di*wi; zi[c+1] = dr*wi + di*wr;
  }
  // lane stages m=32..4 via bpermute: chain w; twiddle is -w on hi lanes,
  // so out_hi = (x_hi - x_lo)*w.
  #pragma unroll
  for (int k = 5; k >= 2; --k) {
    float nwr = wr*wr - wi*wi, nwi = 2.f*wr*wi;
    wr = nwr; wi = nwi;
    const int m = 1 << k;
    #pragma unroll
    for (int c = 0; c < 8; ++c) {
      float pr_ = __shfl_xor(zr[c], m, 64);
      float pi_ = __shfl_xor(zi[c], m, 64);
      bool hi = (lane & m) != 0;
      float sr_ = zr[c] + pr_, si_ = zi[c] + pi_;
      float dr = zr[c] - pr_, di = zi[c] - pi_;
      float qr = dr*wr - di*wi, qi = dr*wi + di*wr;
      zr[c] = hi ? qr : sr_;
      zi[c] = hi ? qi : si_;
    }
  }
  // ---- stage m=2 via DPP quad_perm (xor2) ----
  {
    float nwr = wr*wr - wi*wi, nwi = 2.f*wr*wi;
    wr = nwr; wi = nwi;
    #pragma unroll
    for (int c = 0; c < 8; ++c) {
      float pr_ = dppq<DPP_XOR2>(zr[c]);
      float pi_ = dppq<DPP_XOR2>(zi[c]);
      bool hi = (lane & 2) != 0;
      float sr_ = zr[c] + pr_, si_ = zi[c] + pi_;
      float dr = zr[c] - pr_, di = zi[c] - pi_;
      float qr = dr*wr - di*wi, qi = dr*wi + di*wr;
      zr[c] = hi ? qr : sr_;
      zi[c] = hi ? qi : si_;
    }
  }
  // ---- stage m=1 via DPP quad_perm (xor1), tw = 1 ----
  #pragma unroll
  for (int c = 0; c < 8; ++c) {
    float pr_ = dppq<DPP_XOR1>(zr[c]);
    float pi_ = dppq<DPP_XOR1>(zi[c]);
    bool hi = (lane & 1) != 0;
    zr[c] = hi ? (pr_ - zr[c]) : (zr[c] + pr_);
    zi[c] = hi ? (pi_ - zi[c]) : (zi[c] + pi_);
  }
}

__global__ __launch_bounds__(256) void ks_mega(const float* __restrict__ noise,
                                               const float* __restrict__ env,
                                               const float* __restrict__ tfr,
                                               const float* __restrict__ tfi,
                                               float* __restrict__ out) {
  __shared__ float2 Pld[4][2][PLDSZ];
  __shared__ float2 LcS[4][2][PLDSZ];
  const int w = threadIdx.x >> 6, lane = threadIdx.x & 63;
  const int j = blockIdx.x * 4 + w;
  const int k0 = lane * 4;
  const bool l63 = (lane == 63);
  const int rr = brev6(lane);
  const int base = 8 * rr;
  const int tprod = j * FCH;
  const int t0 = (j == 0) ? 0 : (tprod - 6);
  const int tend = tprod + FCH;
  float2* Pw0 = &Pld[w][0][0];
  float2* Pw1 = &Pld[w][1][0];
  float2* Lc0 = &LcS[w][0][0];
  float2* Lc1 = &LcS[w][1][0];
  const float sc = 1.0f / 512.0f;
  const int CB3[8] = {0,4,2,6,1,5,3,7};

  float Cr[4] = {0.f,0.f,0.f,0.f}, Ci[4] = {0.f,0.f,0.f,0.f};
  float C256 = 0.f;
  float tr[2][4], ti[2][4];
  float t6r[2] = {0.f,0.f}, t6i[2] = {0.f,0.f};
  float nA[8], nB[8], eA, eB;
  float pvb[8] = {0.f,0.f,0.f,0.f,0.f,0.f,0.f,0.f};

  // j==0 pre-pair: frame -1 = 0, frame 0 = imps0 (zero spectrum). Emit row 0
  // (= imps0 lower half) and seed pvb with frame 0.
  if (j == 0) {
    const float e0 = env[0]; const float e02 = e0 * e0;
    const float* n0 = noise + base;
    float q[8];
    *(float4*)(&q[0]) = *(const float4*)(n0);
    *(float4*)(&q[4]) = *(const float4*)(n0 + 4);
    #pragma unroll
    for (int s = 0; s < 8; ++s) pvb[s] = (2.f * q[s] - 1.f) * e02;
    if (!(lane & 1)) {
      float* o = out + base;
      ((float4*)o)[0] = make_float4(pvb[0], pvb[1], pvb[2], pvb[3]);
      ((float4*)o)[1] = make_float4(pvb[4], pvb[5], pvb[6], pvb[7]);
    }
  }

#define LOADTF(S, TS_) do {                                                    \
    const size_t _bt = (size_t)(TS_) * NBINS;                                  \
    _Pragma("unroll") for (int _i = 0; _i < 4; ++_i) {                         \
      tr[S][_i] = tfr[_bt + k0 + _i];                                          \
      ti[S][_i] = tfi[_bt + k0 + _i];                                          \
    }                                                                          \
    if (l63) { t6r[S] = tfr[_bt + 256]; t6i[S] = tfi[_bt + 256]; }             \
  } while (0)

#define LOADNOISE(TA, TB) do {                                                 \
    const float* _pa = noise + (size_t)(TA) * BLOCK_N;                         \
    const float* _pb = noise + (size_t)(TB) * BLOCK_N;                         \
    _Pragma("unroll") for (int _c = 0; _c < 8; ++_c) {                         \
      nA[_c] = _pa[64*_c + lane];                                              \
      nB[_c] = _pb[64*_c + lane];                                              \
    }                                                                          \
    eA = env[TA]; eB = env[TB];                                                \
  } while (0)

// One recurrence step; stash C_t to LDS (recur layout) when it will feed an
// inverse FFT (t >= tprod-2).
#define STEP(S, T, PR, PI, P6R, P6I) do {                                      \
    const int _t = (T);                                                        \
    float Vr[4], Vi[4];                                                        \
    _Pragma("unroll") for (int _i = 0; _i < 4; ++_i) {                         \
      float Ur = Cr[_i] + PR[_i], Ui = Ci[_i] + PI[_i];                        \
      Vr[_i] = tr[S][_i]*Ur - ti[S][_i]*Ui;                                    \
      Vi[_i] = tr[S][_i]*Ui + ti[S][_i]*Ur;                                    \
    }                                                                          \
    if (lane == 0) Vi[0] = 0.f;                                                \
    float U6r = C256 + P6R, U6i = P6I;                                         \
    float V6r = t6r[S]*U6r - t6i[S]*U6i;                                       \
    int _tf = _t + 2; if (_tf > N_ITER - 1) _tf = N_ITER - 1;                  \
    LOADTF(S, _tf);                                                            \
    float Lr = __shfl_up(Vr[3], 1),   Li = __shfl_up(Vi[3], 1);                \
    float Rr = __shfl_down(Vr[0], 1), Ri = __shfl_down(Vi[0], 1);              \
    if (lane == 0) { Lr = Vr[1]; Li = -Vi[1]; }                                \
    if (l63)       { Rr = V6r;   Ri = 0.f; }                                   \
    Cr[0] = 0.54f*Vr[0] - 0.23f*(Lr    + Vr[1]);                               \
    Ci[0] = 0.54f*Vi[0] - 0.23f*(Li    + Vi[1]);                               \
    Cr[1] = 0.54f*Vr[1] - 0.23f*(Vr[0] + Vr[2]);                               \
    Ci[1] = 0.54f*Vi[1] - 0.23f*(Vi[0] + Vi[2]);                               \
    Cr[2] = 0.54f*Vr[2] - 0.23f*(Vr[1] + Vr[3]);                               \
    Ci[2] = 0.54f*Vi[2] - 0.23f*(Vi[1] + Vi[3]);                               \
    Cr[3] = 0.54f*Vr[3] - 0.23f*(Vr[2] + Rr);                                  \
    Ci[3] = 0.54f*Vi[3] - 0.23f*(Vi[2] + Ri);                                  \
    C256  = 0.54f*V6r   - 0.46f*Vr[3];                                         \
    if (_t >= tprod - 2) {                                                     \
      float2* _Ls = ((_t) & 1) ? Lc1 : Lc0;                                    \
      _Ls[PDK(k0 + 0)] = make_float2(Cr[0], Ci[0]);                            \
      _Ls[PDK(k0 + 1)] = make_float2(Cr[1], Ci[1]);                            \
      _Ls[PDK(k0 + 2)] = make_float2(Cr[2], Ci[2]);                            \
      _Ls[PDK(k0 + 3)] = make_float2(Cr[3], Ci[3]);                            \
      if (l63) _Ls[PDK(256)] = make_float2(C256, 0.f);                         \
    }                                                                          \
  } while (0)

  LOADTF(0, t0);
  LOADTF(1, t0 + 1);
  LOADNOISE(t0, t0 + 1);

  for (int t = t0; t < tend; t += 2) {
    // ---- packed forward FFT of impulses (t, t+1) ----
    const float ea2 = eA * eA, eb2 = eB * eB;
    float zr[8], zi[8];
    #pragma unroll
    for (int c = 0; c < 8; ++c) {
      zr[c] = (2.f * nA[c] - 1.f) * ea2;
      zi[c] = (2.f * nB[c] - 1.f) * eb2;
    }
    {
      int ta = t + 2; if (ta > N_ITER - 1) ta = N_ITER - 1;
      int tb = t + 3; if (tb > N_ITER - 1) tb = N_ITER - 1;
      LOADNOISE(ta, tb);
    }
    fft512_regs<1>(zr, zi, lane);
    float mr[8], mi[8];
    {
      int r_ = brev6(lane);
      int lam = brev6((64 - r_) & 63);
      mr[0] = __shfl(zr[0], lam, 64); mi[0] = __shfl(zi[0], lam, 64);
    }
    mr[1] = __shfl_xor(zr[1], 63, 64); mi[1] = __shfl_xor(zi[1], 63, 64);
    mr[2] = __shfl_xor(zr[3], 63, 64); mi[2] = __shfl_xor(zi[3], 63, 64);
    mr[3] = __shfl_xor(zr[2], 63, 64); mi[3] = __shfl_xor(zi[2], 63, 64);
    mr[4] = __shfl_xor(zr[7], 63, 64); mi[4] = __shfl_xor(zi[7], 63, 64);
    mr[5] = __shfl_xor(zr[6], 63, 64); mi[5] = __shfl_xor(zi[6], 63, 64);
    mr[6] = __shfl_xor(zr[5], 63, 64); mi[6] = __shfl_xor(zi[5], 63, 64);
    mr[7] = __shfl_xor(zr[4], 63, 64); mi[7] = __shfl_xor(zi[4], 63, 64);
    if (!(lane & 1)) {
      #pragma unroll
      for (int s = 0; s < 8; ++s) {
        int c = CB3[s];
        int k = 8 * rr + s;
        Pw0[PDK(k)] = make_float2(0.5f*(zr[c] + mr[c]), 0.5f*(zi[c] - mi[c]));
        Pw1[PDK(k)] = make_float2(0.5f*(zi[c] + mi[c]), 0.5f*(mr[c] - zr[c]));
      }
    } else if (lane == 1) {
      Pw0[PDK(256)] = make_float2(0.5f*(zr[0] + mr[0]), 0.5f*(zi[0] - mi[0]));
      Pw1[PDK(256)] = make_float2(0.5f*(zi[0] + mi[0]), 0.5f*(mr[0] - zr[0]));
    }
    float pr0[4], pi0[4], pr1[4], pi1[4];
    float p60r = 0.f, p60i = 0.f, p61r = 0.f, p61i = 0.f;
    #pragma unroll
    for (int i = 0; i < 4; ++i) {
      float2 q0 = Pw0[PDK(k0 + i)];
      float2 q1 = Pw1[PDK(k0 + i)];
      pr0[i] = q0.x; pi0[i] = q0.y;
      pr1[i] = q1.x; pi1[i] = q1.y;
    }
    if (l63) {
      float2 q0 = Pw0[PDK(256)]; p60r = q0.x; p60i = q0.y;
      float2 q1 = Pw1[PDK(256)]; p61r = q1.x; p61i = q1.y;
    }
    // ---- two recurrence steps (stash C to LDS when inv-active) ----
    STEP(0, t,     pr0, pi0, p60r, p60i);
    STEP(1, t + 1, pr1, pi1, p61r, p61i);
    // ---- packed inverse FFT of (C[t], C[t+1]) -> frames (t+1, t+2) ----
    if (t >= tprod - 2) {
      float izr[8], izi[8];
      #pragma unroll
      for (int c = 0; c < 8; ++c) {
        int k = 64 * c + lane;
        bool mir = (k > 256);
        int idx = mir ? (512 - k) : k;
        float2 a = Lc0[PDK(idx)];
        float2 b = Lc1[PDK(idx)];
        float ay = mir ? -a.y : a.y;
        float by = mir ?  b.y : -b.y;
        izr[c] = sc * (a.x + by);
        izi[c] = sc * (b.x + ay);
      }
      fft512_regs<-1>(izr, izi, lane);
      const int fa = t + 1;
      int fb = t + 2; int nfb = (fb > N_ITER - 1) ? (N_ITER - 1) : fb;
      const float efa = env[fa];  const float efa2 = efa * efa;
      const float efb = env[nfb]; const float efb2 = efb * efb;
      const float* na_ = noise + (size_t)fa  * BLOCK_N + base;
      const float* nb_ = noise + (size_t)nfb * BLOCK_N + base;
      float Aa[8], Bb[8];
      *(float4*)(&Aa[0]) = *(const float4*)(na_);
      *(float4*)(&Aa[4]) = *(const float4*)(na_ + 4);
      *(float4*)(&Bb[0]) = *(const float4*)(nb_);
      *(float4*)(&Bb[4]) = *(const float4*)(nb_ + 4);
      float va[8], vb[8];
      #pragma unroll
      for (int s = 0; s < 8; ++s) {
        int c = CB3[s];
        va[s] = izr[c] + (2.f * Aa[s] - 1.f) * efa2;
        vb[s] = izi[c] + (2.f * Bb[s] - 1.f) * efb2;
      }
      // Half-merge exchanges via DPP xor1 (VALU, replaces 16 bpermutes).
      float sva[8], spv[8];
      #pragma unroll
      for (int s = 0; s < 8; ++s) {
        sva[s] = dppq<DPP_XOR1>(va[s]);
        spv[s] = dppq<DPP_XOR1>(pvb[s]);
      }
      if (!(lane & 1)) {
        if (t >= tprod) {                       // row fa = va lower + pvb upper
          float* o = out + (size_t)fa * 256 + base;
          ((float4*)o)[0] = make_float4(va[0]+spv[0], va[1]+spv[1], va[2]+spv[2], va[3]+spv[3]);
          ((float4*)o)[1] = make_float4(va[4]+spv[4], va[5]+spv[5], va[6]+spv[6], va[7]+spv[7]);
        }
        if (fb <= tprod + 7) {                  // row fb = vb lower + va upper
          float* o = out + (size_t)fb * 256 + base;
          ((float4*)o)[0] = make_float4(vb[0]+sva[0], vb[1]+sva[1], vb[2]+sva[2], vb[3]+sva[3]);
          ((float4*)o)[1] = make_float4(vb[4]+sva[4], vb[5]+sva[5], vb[6]+sva[6], vb[7]+sva[7]);
        }
      }
      #pragma unroll
      for (int s = 0; s < 8; ++s) pvb[s] = vb[s];
    }
  }
#undef LOADTF
#undef LOADNOISE
#undef STEP
}

extern "C" void kernel_launch(void* const* d_in, const int* in_sizes, int n_in,
                              void* d_out, int out_size, void* d_ws, size_t ws_size,
                              hipStream_t stream) {
  (void)in_sizes; (void)n_in; (void)ws_size; (void)out_size; (void)d_ws;
  const float* noise = (const float*)d_in[1];
  const float* env   = (const float*)d_in[2];
  const float* tfr   = (const float*)d_in[3];
  const float* tfi   = (const float*)d_in[4];
  float* out = (float*)d_out;
  // Single fused kernel; no workspace needed (every out row fully written).
  ks_mega<<<dim3(NCHUNK / 4), dim3(256), 0, stream>>>(noise, env, tfr, tfi, out);
}